// Round 14
// baseline (335.494 us; speedup 1.0000x reference)
//
#include <hip/hip_runtime.h>

#define NF 128          // features
#define SH 9            // bucket shift
#define BNODES 512      // nodes per bucket (1<<SH)
#define MAXNB 256       // max buckets (n <= 131072)

typedef unsigned short u16;
typedef unsigned int u32;
using u16x4 = __attribute__((ext_vector_type(4))) u16;
using u16x8 = __attribute__((ext_vector_type(8))) u16;
using s16x8 = __attribute__((ext_vector_type(8))) short;
using f32x4 = __attribute__((ext_vector_type(4))) float;
using u32x4 = __attribute__((ext_vector_type(4))) u32;
using i32x4 = __attribute__((ext_vector_type(4))) int;

__device__ inline float b2f(u16 b) {
    union { u32 u; float f; } c; c.u = (u32)b << 16; return c.f;
}
__device__ inline float lo2f(u32 w) {
    union { u32 u; float f; } c; c.u = w << 16; return c.f;
}
__device__ inline float hi2f(u32 w) {
    union { u32 u; float f; } c; c.u = w & 0xFFFF0000u; return c.f;
}
__device__ inline u16 f2b(float f) {
    union { float f; u32 u; } c; c.f = f;
    u32 u = c.u;
    u += 0x7FFFu + ((u >> 16) & 1u);   // round-to-nearest-even
    return (u16)(u >> 16);
}
__device__ inline u16x8 nt_load8(const u16* p) {
    u32x4 v = __builtin_nontemporal_load((const u32x4*)p);
    return *(u16x8*)&v;
}
__device__ inline void nt_store8(u16* p, u16x8 v) {
    __builtin_nontemporal_store(*(u32x4*)&v, (u32x4*)p);
}
__device__ inline int padded4(int d) { return (d + 3) & ~3; }

// ---------------- bucket histogram (LDS staged) ----------------
__global__ __launch_bounds__(256) void bhist_kernel(const int* __restrict__ dst,
                                                    int* __restrict__ bcnt, int E, int NB) {
    __shared__ int h[MAXNB];
    int t = threadIdx.x;
    h[t] = 0;
    __syncthreads();
    for (int e = blockIdx.x * 256 + t; e < E; e += gridDim.x * 256)
        atomicAdd(&h[__builtin_nontemporal_load(dst + e) >> SH], 1);
    __syncthreads();
    if (t < NB && h[t]) atomicAdd(&bcnt[t], h[t]);
}

// ---------------- bucket scan: boff (exclusive), gcur init ----------------
__global__ __launch_bounds__(256) void bscan_kernel(const int* __restrict__ bcnt,
                                                    int* __restrict__ boff,
                                                    int* __restrict__ gcur, int NB, int E) {
    __shared__ int ss[256];
    int t = threadIdx.x;
    int v = (t < NB) ? bcnt[t] : 0;
    ss[t] = v; __syncthreads();
    for (int off = 1; off < 256; off <<= 1) {
        int u = (t >= off) ? ss[t - off] : 0;
        __syncthreads();
        ss[t] += u;
        __syncthreads();
    }
    int excl = ss[t] - v;
    if (t < NB) { boff[t] = excl; gcur[t] = excl; }
    if (t == 0) boff[NB] = E;
}

// ---------------- generic in-place exclusive scan (<=256 entries) ----------------
__global__ __launch_bounds__(256) void scan_excl_kernel(int* __restrict__ a, int nb) {
    __shared__ int ss[256];
    int t = threadIdx.x;
    int v = (t < nb) ? a[t] : 0;
    ss[t] = v; __syncthreads();
    for (int off = 1; off < 256; off <<= 1) {
        int u = (t >= off) ? ss[t - off] : 0;
        __syncthreads();
        ss[t] += u;
        __syncthreads();
    }
    if (t < nb) a[t] = ss[t] - v;
}

// ---------------- scatter edges into bucket-sorted pairs (LDS staged) ----------------
// 4096 edges / block; packed = (dst&511)<<17 | src  (src < 2^17)
__global__ __launch_bounds__(256) void scatter_kernel(
    const int* __restrict__ src, const int* __restrict__ dst,
    int* __restrict__ gcur, u32* __restrict__ pairs, int E, int NB)
{
    __shared__ int hist[MAXNB];
    __shared__ int cstart[256];
    __shared__ int gbase[MAXNB];
    __shared__ u32 stage[4096];
    __shared__ u16 bmap[4096];
    int t = threadIdx.x;
    int base = blockIdx.x * 4096;

    hist[t] = 0;
    __syncthreads();

    u32 packed[16]; int bb[16]; int loff[16];
    #pragma unroll
    for (int j = 0; j < 16; j++) {
        int e = base + j * 256 + t;
        bb[j] = -1;
        if (e < E) {
            int d = __builtin_nontemporal_load(dst + e);
            int s = __builtin_nontemporal_load(src + e);
            int b = d >> SH;
            bb[j] = b;
            packed[j] = ((u32)(d & (BNODES - 1)) << 17) | (u32)s;
            loff[j] = atomicAdd(&hist[b], 1);
        }
    }
    __syncthreads();

    int hv = hist[t];
    cstart[t] = hv; __syncthreads();
    for (int off = 1; off < 256; off <<= 1) {
        int u = (t >= off) ? cstart[t - off] : 0;
        __syncthreads();
        cstart[t] += u;
        __syncthreads();
    }
    int excl = cstart[t] - hv;
    if (t < NB && hv > 0) gbase[t] = atomicAdd(&gcur[t], hv);
    __syncthreads();
    cstart[t] = excl;
    __syncthreads();

    #pragma unroll
    for (int j = 0; j < 16; j++) if (bb[j] >= 0) {
        int pos = cstart[bb[j]] + loff[j];
        stage[pos] = packed[j];
        bmap[pos] = (u16)bb[j];
    }
    __syncthreads();

    int total = min(4096, E - base);
    for (int k = t; k < total; k += 256) {
        u32 p = stage[k];
        int b = bmap[k];
        pairs[gbase[b] + (k - cstart[b])] = p;
    }
}

// ---------------- per-bucket degree count + padded bucket sum ----------------
__global__ __launch_bounds__(256) void degb_kernel(const u32* __restrict__ pairs,
                                                   const int* __restrict__ boff,
                                                   int* __restrict__ deg,
                                                   int* __restrict__ bsumB, int n) {
    __shared__ int dl[BNODES];
    __shared__ int red[256];
    int b = blockIdx.x, t = threadIdx.x;
    for (int i = t; i < BNODES; i += 256) dl[i] = 0;
    __syncthreads();
    int s = boff[b], e = boff[b + 1];
    for (int k = s + t; k < e; k += 256)
        atomicAdd(&dl[__builtin_nontemporal_load(pairs + k) >> 17], 1);
    __syncthreads();
    int nb0 = b << SH;
    int ps = 0;
    for (int i = t; i < BNODES; i += 256) {
        int d = dl[i];
        if (nb0 + i < n) { deg[nb0 + i] = d; ps += padded4(d); }
    }
    red[t] = ps; __syncthreads();
    for (int off = 128; off; off >>= 1) {
        if (t < off) red[t] += red[t + off];
        __syncthreads();
    }
    if (!t) bsumB[b] = red[0];
}

// ---------------- per-bucket: local padded scan + info + pads + CSR fill ----------------
__global__ __launch_bounds__(256) void fillC_kernel(const u32* __restrict__ pairs,
                                                    const int* __restrict__ boff,
                                                    const int* __restrict__ deg,
                                                    const int* __restrict__ bbase,
                                                    int* __restrict__ info,
                                                    int* __restrict__ adj, int n) {
    __shared__ int begl[BNODES];
    __shared__ int curl[BNODES];
    __shared__ int ss[256];
    int b = blockIdx.x, t = threadIdx.x;
    int nb0 = b << SH;
    int i0 = 2 * t, i1 = 2 * t + 1;
    int d0 = 0, d1 = 0;
    if (nb0 + i0 < n) d0 = deg[nb0 + i0];
    if (nb0 + i1 < n) d1 = deg[nb0 + i1];
    int p0 = padded4(d0), p1 = padded4(d1);
    int s = p0 + p1;
    ss[t] = s; __syncthreads();
    for (int off = 1; off < 256; off <<= 1) {
        int u = (t >= off) ? ss[t - off] : 0;
        __syncthreads();
        ss[t] += u;
        __syncthreads();
    }
    int beg0 = bbase[b] + ss[t] - s;
    int beg1 = beg0 + p0;
    if (nb0 + i1 < n) {
        i32x4 w = {beg0, d0, beg1, d1};
        ((i32x4*)info)[(nb0 >> 1) + t] = w;
    } else if (nb0 + i0 < n) {
        info[2 * (nb0 + i0)] = beg0; info[2 * (nb0 + i0) + 1] = d0;
    }
    begl[i0] = beg0; curl[i0] = 0;
    begl[i1] = beg1; curl[i1] = 0;
    if (nb0 + i0 < n) for (int p = d0; p < p0; p++) adj[beg0 + p] = n;
    if (nb0 + i1 < n) for (int p = d1; p < p1; p++) adj[beg1 + p] = n;
    __syncthreads();
    int sE = boff[b], eE = boff[b + 1];
    for (int k = sE + t; k < eE; k += 256) {
        u32 p = __builtin_nontemporal_load(pairs + k);
        int ld = p >> 17, sr = p & 0x1FFFF;
        int pos = atomicAdd(&curl[ld], 1);
        adj[begl[ld] + pos] = sr;
    }
}

// ---------------- cast x fp32 -> bf16 row-major [nr][128]; row n = 0 ----------------
__global__ __launch_bounds__(256) void cast_x_kernel(const float* __restrict__ x,
                                                     u16* __restrict__ xb, int n, int nr) {
    int i = blockIdx.x * 256 + threadIdx.x;   // one per 8 features
    if (i >= nr * (NF / 8)) return;
    int node = i >> 4, ch = i & 15;
    u16x8 o = (u16x8)0;
    if (node < n) {
        const float* p = x + (size_t)node * NF + ch * 8;
        f32x4 v0 = __builtin_nontemporal_load((const f32x4*)p);
        f32x4 v1 = __builtin_nontemporal_load((const f32x4*)(p + 4));
        o[0] = f2b(v0[0]); o[1] = f2b(v0[1]); o[2] = f2b(v0[2]); o[3] = f2b(v0[3]);
        o[4] = f2b(v1[0]); o[5] = f2b(v1[1]); o[6] = f2b(v1[2]); o[7] = f2b(v1[3]);
    }
    *(u16x8*)(xb + (size_t)node * NF + ch * 8) = o;
}

// ---------------- weights: fp32 [K][N] -> bf16 transposed [N][K] ----------------
__global__ void cast_wt_kernel(const float* __restrict__ w0, const float* __restrict__ w1,
                               const float* __restrict__ w2, const float* __restrict__ w3,
                               u16* __restrict__ o0, u16* __restrict__ o1,
                               u16* __restrict__ o2, u16* __restrict__ o3) {
    int m = blockIdx.y;
    const float* w = (m == 0) ? w0 : (m == 1) ? w1 : (m == 2) ? w2 : w3;
    u16* o = (m == 0) ? o0 : (m == 1) ? o1 : (m == 2) ? o2 : o3;
    int i = blockIdx.x * 256 + threadIdx.x;
    int k = i >> 7, nc = i & 127;
    o[nc * NF + k] = f2b(w[k * NF + nc]);
}

// ---------------- fused layer: gather-mean into LDS + dual MFMA (B from global) ----------------
// 512 threads, 128 nodes/block: 32 groups x 16 lanes, 4 serial nodes per group.
// No W_s: B-fragments read directly from L2-resident transposed weights.
template <bool FC>
__global__ __launch_bounds__(512) void sage_fused_kernel(
    const u16* __restrict__ xin,       // [nr][128] bf16, row n = zeros
    const int* __restrict__ info,      // [n]{padded_beg, deg}
    const int* __restrict__ adj,       // padded, 4-aligned rows; pads -> row n
    const u16* __restrict__ Wtl,       // [128][128] bf16 transposed: Wt[col][k]
    const u16* __restrict__ Wtr,
    const float* __restrict__ bias,
    const float* __restrict__ Wfc,     // [128][2] f32
    const float* __restrict__ bfc,
    u16* __restrict__ hout,            // [nr][128] bf16 (layer 1); row n zeroed
    float* __restrict__ out,           // [n][2] f32 (layer 2)
    int n)
{
    constexpr int MT = 128;
    constexpr int LDK = 136;
    __shared__ u16 A_s[MT][LDK];       // 34.8 KB only

    int t = threadIdx.x;
    int node0 = blockIdx.x * MT;

    // ---- gather-mean phase: agg tile straight into A_s
    {
        int grp = t >> 4, lane = t & 15;
        const char* xbase = (const char*)xin;
        u32 lo16 = (u32)lane * 16;

        for (int j = 0; j < 4; j++) {
            int m = grp * 4 + j;
            int node = node0 + m;
            float L[4] = {0.f, 0.f, 0.f, 0.f}, H[4] = {0.f, 0.f, 0.f, 0.f};
            int dg = 0;
            if (node < n) {
                int2 inf = *(const int2*)(info + 2 * node);
                dg = inf.y;
                const i32x4* ap = (const i32x4*)(adj + inf.x);
                int ng = (dg + 3) >> 2;

#define ROWU(nb) (*(const u32x4*)(xbase + (((u32)(nb) << 8) + lo16)))
#define ACC4(cur) { \
    u32x4 r0 = ROWU(cur[0]), r1 = ROWU(cur[1]), r2 = ROWU(cur[2]), r3 = ROWU(cur[3]); \
    _Pragma("unroll") \
    for (int k = 0; k < 4; k++) { \
        L[k] += (lo2f(r0[k]) + lo2f(r1[k])) + (lo2f(r2[k]) + lo2f(r3[k])); \
        H[k] += (hi2f(r0[k]) + hi2f(r1[k])) + (hi2f(r2[k]) + hi2f(r3[k])); \
    } }
                i32x4 ia, ib;
                if (ng >= 2) {
                    ia = __builtin_nontemporal_load(ap);
                    ib = __builtin_nontemporal_load(ap + 1);
                }
                int g = 0;
                while (g + 2 <= ng) {
                    i32x4 ca = ia, cb = ib;
                    g += 2;
                    if (g + 2 <= ng) {   // prefetch next pair under feature loads
                        ia = __builtin_nontemporal_load(ap + g);
                        ib = __builtin_nontemporal_load(ap + g + 1);
                    }
                    ACC4(ca);
                    ACC4(cb);
                }
                if (g < ng) {
                    i32x4 ca = __builtin_nontemporal_load(ap + g);
                    ACC4(ca);
                }
#undef ACC4
#undef ROWU
            }
            float invd = 1.0f / fmaxf((float)dg, 1.0f);
            u16x8 o;
            #pragma unroll
            for (int k = 0; k < 4; k++) {
                o[2 * k]     = f2b(L[k] * invd);
                o[2 * k + 1] = f2b(H[k] * invd);
            }
            *(u16x8*)&A_s[m][lane * 8] = o;    // node >= n -> zeros
        }
    }
    __syncthreads();

    // ---- MFMA pass 1: acc = agg @ Wl  (8 waves x 16 rows = 128), B from global
    int l = t & 63;
    int lr = l & 15;
    int lko = (l >> 4) * 8;
    int m0 = (t >> 6) * 16;

    f32x4 acc[8];
    #pragma unroll
    for (int f = 0; f < 8; f++) acc[f] = (f32x4)0.f;

    #pragma unroll
    for (int ks = 0; ks < NF; ks += 32) {
        s16x8 a = *(const s16x8*)&A_s[m0 + lr][ks + lko];
        s16x8 bf[8];
        #pragma unroll
        for (int f = 0; f < 8; f++)
            bf[f] = *(const s16x8*)(Wtl + (size_t)(f * 16 + lr) * NF + ks + lko);
        #pragma unroll
        for (int f = 0; f < 8; f++)
            acc[f] = __builtin_amdgcn_mfma_f32_16x16x32_bf16(a, bf[f], acc[f], 0, 0, 0);
    }
    __syncthreads();

    // ---- stage self tile
    #pragma unroll
    for (int i = 0; i < 4; i++) {
        int idx = t + i * 512;                 // 2048 chunks
        int row = idx >> 4, ch = idx & 15;
        int node = node0 + row;
        u16x8 v = (u16x8)0;
        if (node < n) v = nt_load8(xin + (size_t)node * NF + ch * 8);
        *(u16x8*)&A_s[row][ch * 8] = v;
    }
    __syncthreads();

    // ---- MFMA pass 2: acc += self @ Wr, B from global
    #pragma unroll
    for (int ks = 0; ks < NF; ks += 32) {
        s16x8 a = *(const s16x8*)&A_s[m0 + lr][ks + lko];
        s16x8 bf[8];
        #pragma unroll
        for (int f = 0; f < 8; f++)
            bf[f] = *(const s16x8*)(Wtr + (size_t)(f * 16 + lr) * NF + ks + lko);
        #pragma unroll
        for (int f = 0; f < 8; f++)
            acc[f] = __builtin_amdgcn_mfma_f32_16x16x32_bf16(a, bf[f], acc[f], 0, 0, 0);
    }

    // ---- bias + relu -> bf16 tile in A_s
    __syncthreads();
    int rowb = m0 + (l >> 4) * 4;      // C layout: row=(lane>>4)*4+reg, col=lane&15
    #pragma unroll
    for (int f = 0; f < 8; f++) {
        float bc = bias[f * 16 + lr];
        #pragma unroll
        for (int r = 0; r < 4; r++) {
            float v = fmaxf(acc[f][r] + bc, 0.f);
            A_s[rowb + r][f * 16 + lr] = f2b(v);
        }
    }
    __syncthreads();

    if (!FC) {
        // write h row-major; node n (zero row) written explicitly
        #pragma unroll
        for (int i = 0; i < 4; i++) {
            int idx = t + i * 512;
            int row = idx >> 4, ch = idx & 15;
            int node = node0 + row;
            if (node < n)
                nt_store8(hout + (size_t)node * NF + ch * 8, *(u16x8*)&A_s[row][ch * 8]);
            else if (node == n)
                nt_store8(hout + (size_t)node * NF + ch * 8, (u16x8)0);
        }
    } else {
        int g = t >> 5, lane = t & 31;     // 16 groups of 32 lanes
        float2 wfc[4];
        #pragma unroll
        for (int j = 0; j < 4; j++) wfc[j] = ((const float2*)Wfc)[lane * 4 + j];
        float bf0 = bfc[0], bf1 = bfc[1];
        for (int m8 = 0; m8 < 8; m8++) {
            int m = g * 8 + m8;
            float p0 = 0.f, p1 = 0.f;
            #pragma unroll
            for (int j = 0; j < 4; j++) {
                float h = b2f(A_s[m][lane * 4 + j]);
                p0 += h * wfc[j].x;
                p1 += h * wfc[j].y;
            }
            #pragma unroll
            for (int s = 16; s; s >>= 1) {
                p0 += __shfl_down(p0, s, 32);
                p1 += __shfl_down(p1, s, 32);
            }
            int node = node0 + m;
            if (lane == 0 && node < n)
                *(float2*)(out + (size_t)node * 2) = make_float2(p0 + bf0, p1 + bf1);
        }
    }
}

extern "C" void kernel_launch(void* const* d_in, const int* in_sizes, int n_in,
                              void* d_out, int out_size, void* d_ws, size_t ws_size,
                              hipStream_t stream) {
    const float* x   = (const float*)d_in[0];
    const int*   ei  = (const int*)d_in[1];
    const float* W1l = (const float*)d_in[2];
    const float* b1  = (const float*)d_in[3];
    const float* W1r = (const float*)d_in[4];
    const float* W2l = (const float*)d_in[5];
    const float* b2  = (const float*)d_in[6];
    const float* W2r = (const float*)d_in[7];
    const float* Wfc = (const float*)d_in[8];
    const float* bfc = (const float*)d_in[9];

    const int n = in_sizes[0] / NF;   // 100000
    const int E = in_sizes[1] / 2;    // 1600000
    const int nr = n + 1;             // +1 zero row for pad slots
    const int NB = (n + BNODES - 1) >> SH;   // 196
    const int* src = ei;
    const int* dst = ei + E;

    // ws: xb | h1 | 4x Wt | adj(E+3n) | deg(n) | info(2n) |
    //     bsumB(256) | bcnt(256) | gcur(256) | boff(257) | pairs(E)
    u16* xb     = (u16*)d_ws;
    u16* h1     = xb + (size_t)nr * NF;
    u16* Wt1l   = h1 + (size_t)nr * NF;
    u16* Wt1r   = Wt1l + NF * NF;
    u16* Wt2l   = Wt1r + NF * NF;
    u16* Wt2r   = Wt2l + NF * NF;
    int* adj    = (int*)(Wt2r + NF * NF);
    int* deg    = adj + ((size_t)E + 3 * (size_t)n);
    int* info   = deg + n;
    int* bsumB  = info + 2 * (size_t)n;
    int* bcnt   = bsumB + 256;
    int* gcur   = bcnt + 256;
    int* boff   = gcur + 256;
    u32* pairs  = (u32*)(boff + 257);

    (void)hipMemsetAsync(bcnt, 0, 256 * sizeof(int), stream);

    // ---- bucketed CSR build (merged kernels)
    bhist_kernel<<<1024, 256, 0, stream>>>(dst, bcnt, E, NB);
    bscan_kernel<<<1, 256, 0, stream>>>(bcnt, boff, gcur, NB, E);
    scatter_kernel<<<(E + 4095) / 4096, 256, 0, stream>>>(src, dst, gcur, pairs, E, NB);
    degb_kernel<<<NB, 256, 0, stream>>>(pairs, boff, deg, bsumB, n);
    scan_excl_kernel<<<1, 256, 0, stream>>>(bsumB, NB);
    fillC_kernel<<<NB, 256, 0, stream>>>(pairs, boff, deg, bsumB, info, adj, n);

    cast_x_kernel<<<(nr * (NF / 8) + 255) / 256, 256, 0, stream>>>(x, xb, n, nr);
    cast_wt_kernel<<<dim3(64, 4), 256, 0, stream>>>(W1l, W1r, W2l, W2r,
                                                    Wt1l, Wt1r, Wt2l, Wt2r);

    int fb = (nr + 127) / 128;            // covers node n as well
    // layer 1: xb -> h1 (fused gather + GEMM)
    sage_fused_kernel<false><<<fb, 512, 0, stream>>>(
        xb, info, adj, Wt1l, Wt1r, b1, nullptr, nullptr, h1, nullptr, n);
    // layer 2 + FC: h1 -> out
    sage_fused_kernel<true><<<fb, 512, 0, stream>>>(
        h1, info, adj, Wt2l, Wt2r, b2, Wfc, bfc, nullptr, (float*)d_out, n);
}

// Round 15
// 284.525 us; speedup vs baseline: 1.1791x; 1.1791x over previous
//
#include <hip/hip_runtime.h>

#define NF 128          // features
#define SH 9            // bucket shift
#define BNODES 512      // nodes per bucket (1<<SH)
#define MAXNB 256       // max buckets (n <= 131072)

typedef unsigned short u16;
typedef unsigned int u32;
using u16x4 = __attribute__((ext_vector_type(4))) u16;
using u16x8 = __attribute__((ext_vector_type(8))) u16;
using s16x8 = __attribute__((ext_vector_type(8))) short;
using f32x4 = __attribute__((ext_vector_type(4))) float;
using u32x4 = __attribute__((ext_vector_type(4))) u32;
using i32x4 = __attribute__((ext_vector_type(4))) int;

__device__ inline float b2f(u16 b) {
    union { u32 u; float f; } c; c.u = (u32)b << 16; return c.f;
}
__device__ inline float lo2f(u32 w) {
    union { u32 u; float f; } c; c.u = w << 16; return c.f;
}
__device__ inline float hi2f(u32 w) {
    union { u32 u; float f; } c; c.u = w & 0xFFFF0000u; return c.f;
}
__device__ inline u16 f2b(float f) {
    union { float f; u32 u; } c; c.f = f;
    u32 u = c.u;
    u += 0x7FFFu + ((u >> 16) & 1u);   // round-to-nearest-even
    return (u16)(u >> 16);
}
__device__ inline u16x8 nt_load8(const u16* p) {
    u32x4 v = __builtin_nontemporal_load((const u32x4*)p);
    return *(u16x8*)&v;
}
__device__ inline void nt_store8(u16* p, u16x8 v) {
    __builtin_nontemporal_store(*(u32x4*)&v, (u32x4*)p);
}
__device__ inline int padded4(int d) { return (d + 3) & ~3; }

// ---------------- bucket histogram (LDS staged) ----------------
__global__ __launch_bounds__(256) void bhist_kernel(const int* __restrict__ dst,
                                                    int* __restrict__ bcnt, int E, int NB) {
    __shared__ int h[MAXNB];
    int t = threadIdx.x;
    h[t] = 0;
    __syncthreads();
    for (int e = blockIdx.x * 256 + t; e < E; e += gridDim.x * 256)
        atomicAdd(&h[__builtin_nontemporal_load(dst + e) >> SH], 1);
    __syncthreads();
    if (t < NB && h[t]) atomicAdd(&bcnt[t], h[t]);
}

// ---------------- bucket scan: boff (exclusive), gcur init ----------------
__global__ __launch_bounds__(256) void bscan_kernel(const int* __restrict__ bcnt,
                                                    int* __restrict__ boff,
                                                    int* __restrict__ gcur, int NB, int E) {
    __shared__ int ss[256];
    int t = threadIdx.x;
    int v = (t < NB) ? bcnt[t] : 0;
    ss[t] = v; __syncthreads();
    for (int off = 1; off < 256; off <<= 1) {
        int u = (t >= off) ? ss[t - off] : 0;
        __syncthreads();
        ss[t] += u;
        __syncthreads();
    }
    int excl = ss[t] - v;
    if (t < NB) { boff[t] = excl; gcur[t] = excl; }
    if (t == 0) boff[NB] = E;
}

// ---------------- generic in-place exclusive scan (<=256 entries) ----------------
__global__ __launch_bounds__(256) void scan_excl_kernel(int* __restrict__ a, int nb) {
    __shared__ int ss[256];
    int t = threadIdx.x;
    int v = (t < nb) ? a[t] : 0;
    ss[t] = v; __syncthreads();
    for (int off = 1; off < 256; off <<= 1) {
        int u = (t >= off) ? ss[t - off] : 0;
        __syncthreads();
        ss[t] += u;
        __syncthreads();
    }
    if (t < nb) a[t] = ss[t] - v;
}

// ---------------- scatter edges into bucket-sorted pairs (LDS staged) ----------------
// 4096 edges / block; packed = (dst&511)<<17 | src  (src < 2^17)
__global__ __launch_bounds__(256) void scatter_kernel(
    const int* __restrict__ src, const int* __restrict__ dst,
    int* __restrict__ gcur, u32* __restrict__ pairs, int E, int NB)
{
    __shared__ int hist[MAXNB];
    __shared__ int cstart[256];
    __shared__ int gbase[MAXNB];
    __shared__ u32 stage[4096];
    __shared__ u16 bmap[4096];
    int t = threadIdx.x;
    int base = blockIdx.x * 4096;

    hist[t] = 0;
    __syncthreads();

    u32 packed[16]; int bb[16]; int loff[16];
    #pragma unroll
    for (int j = 0; j < 16; j++) {
        int e = base + j * 256 + t;
        bb[j] = -1;
        if (e < E) {
            int d = __builtin_nontemporal_load(dst + e);
            int s = __builtin_nontemporal_load(src + e);
            int b = d >> SH;
            bb[j] = b;
            packed[j] = ((u32)(d & (BNODES - 1)) << 17) | (u32)s;
            loff[j] = atomicAdd(&hist[b], 1);
        }
    }
    __syncthreads();

    int hv = hist[t];
    cstart[t] = hv; __syncthreads();
    for (int off = 1; off < 256; off <<= 1) {
        int u = (t >= off) ? cstart[t - off] : 0;
        __syncthreads();
        cstart[t] += u;
        __syncthreads();
    }
    int excl = cstart[t] - hv;
    if (t < NB && hv > 0) gbase[t] = atomicAdd(&gcur[t], hv);
    __syncthreads();
    cstart[t] = excl;
    __syncthreads();

    #pragma unroll
    for (int j = 0; j < 16; j++) if (bb[j] >= 0) {
        int pos = cstart[bb[j]] + loff[j];
        stage[pos] = packed[j];
        bmap[pos] = (u16)bb[j];
    }
    __syncthreads();

    int total = min(4096, E - base);
    for (int k = t; k < total; k += 256) {
        u32 p = stage[k];
        int b = bmap[k];
        pairs[gbase[b] + (k - cstart[b])] = p;
    }
}

// ---------------- per-bucket degree count + padded bucket sum ----------------
__global__ __launch_bounds__(256) void degb_kernel(const u32* __restrict__ pairs,
                                                   const int* __restrict__ boff,
                                                   int* __restrict__ deg,
                                                   int* __restrict__ bsumB, int n) {
    __shared__ int dl[BNODES];
    __shared__ int red[256];
    int b = blockIdx.x, t = threadIdx.x;
    for (int i = t; i < BNODES; i += 256) dl[i] = 0;
    __syncthreads();
    int s = boff[b], e = boff[b + 1];
    for (int k = s + t; k < e; k += 256)
        atomicAdd(&dl[__builtin_nontemporal_load(pairs + k) >> 17], 1);
    __syncthreads();
    int nb0 = b << SH;
    int ps = 0;
    for (int i = t; i < BNODES; i += 256) {
        int d = dl[i];
        if (nb0 + i < n) { deg[nb0 + i] = d; ps += padded4(d); }
    }
    red[t] = ps; __syncthreads();
    for (int off = 128; off; off >>= 1) {
        if (t < off) red[t] += red[t + off];
        __syncthreads();
    }
    if (!t) bsumB[b] = red[0];
}

// ---------------- per-bucket: local padded scan + info + pads + CSR fill ----------------
__global__ __launch_bounds__(256) void fillC_kernel(const u32* __restrict__ pairs,
                                                    const int* __restrict__ boff,
                                                    const int* __restrict__ deg,
                                                    const int* __restrict__ bbase,
                                                    int* __restrict__ info,
                                                    int* __restrict__ adj, int n) {
    __shared__ int begl[BNODES];
    __shared__ int curl[BNODES];
    __shared__ int ss[256];
    int b = blockIdx.x, t = threadIdx.x;
    int nb0 = b << SH;
    int i0 = 2 * t, i1 = 2 * t + 1;
    int d0 = 0, d1 = 0;
    if (nb0 + i0 < n) d0 = deg[nb0 + i0];
    if (nb0 + i1 < n) d1 = deg[nb0 + i1];
    int p0 = padded4(d0), p1 = padded4(d1);
    int s = p0 + p1;
    ss[t] = s; __syncthreads();
    for (int off = 1; off < 256; off <<= 1) {
        int u = (t >= off) ? ss[t - off] : 0;
        __syncthreads();
        ss[t] += u;
        __syncthreads();
    }
    int beg0 = bbase[b] + ss[t] - s;
    int beg1 = beg0 + p0;
    if (nb0 + i1 < n) {
        i32x4 w = {beg0, d0, beg1, d1};
        ((i32x4*)info)[(nb0 >> 1) + t] = w;
    } else if (nb0 + i0 < n) {
        info[2 * (nb0 + i0)] = beg0; info[2 * (nb0 + i0) + 1] = d0;
    }
    begl[i0] = beg0; curl[i0] = 0;
    begl[i1] = beg1; curl[i1] = 0;
    if (nb0 + i0 < n) for (int p = d0; p < p0; p++) adj[beg0 + p] = n;
    if (nb0 + i1 < n) for (int p = d1; p < p1; p++) adj[beg1 + p] = n;
    __syncthreads();
    int sE = boff[b], eE = boff[b + 1];
    for (int k = sE + t; k < eE; k += 256) {
        u32 p = __builtin_nontemporal_load(pairs + k);
        int ld = p >> 17, sr = p & 0x1FFFF;
        int pos = atomicAdd(&curl[ld], 1);
        adj[begl[ld] + pos] = sr;
    }
}

// ---------------- cast x fp32 -> bf16 row-major [nr][128]; row n = 0 ----------------
__global__ __launch_bounds__(256) void cast_x_kernel(const float* __restrict__ x,
                                                     u16* __restrict__ xb, int n, int nr) {
    int i = blockIdx.x * 256 + threadIdx.x;   // one per 8 features
    if (i >= nr * (NF / 8)) return;
    int node = i >> 4, ch = i & 15;
    u16x8 o = (u16x8)0;
    if (node < n) {
        const float* p = x + (size_t)node * NF + ch * 8;
        f32x4 v0 = __builtin_nontemporal_load((const f32x4*)p);
        f32x4 v1 = __builtin_nontemporal_load((const f32x4*)(p + 4));
        o[0] = f2b(v0[0]); o[1] = f2b(v0[1]); o[2] = f2b(v0[2]); o[3] = f2b(v0[3]);
        o[4] = f2b(v1[0]); o[5] = f2b(v1[1]); o[6] = f2b(v1[2]); o[7] = f2b(v1[3]);
    }
    *(u16x8*)(xb + (size_t)node * NF + ch * 8) = o;
}

// ---------------- weights: fp32 [K][N] -> bf16 transposed [N][K] ----------------
__global__ void cast_wt_kernel(const float* __restrict__ w0, const float* __restrict__ w1,
                               const float* __restrict__ w2, const float* __restrict__ w3,
                               u16* __restrict__ o0, u16* __restrict__ o1,
                               u16* __restrict__ o2, u16* __restrict__ o3) {
    int m = blockIdx.y;
    const float* w = (m == 0) ? w0 : (m == 1) ? w1 : (m == 2) ? w2 : w3;
    u16* o = (m == 0) ? o0 : (m == 1) ? o1 : (m == 2) ? o2 : o3;
    int i = blockIdx.x * 256 + threadIdx.x;
    int k = i >> 7, nc = i & 127;
    o[nc * NF + k] = f2b(w[k * NF + nc]);
}

// ---------------- fused layer: gather-mean into LDS + dual MFMA + epilogue ----------------
// 512 threads, 128 nodes/block: 32 groups x 16 lanes, 4 serial nodes per group.
// Wr + self-tile loads issued BEFORE gather (registers), written to LDS after pass 1.
template <bool FC>
__global__ __launch_bounds__(512) void sage_fused_kernel(
    const u16* __restrict__ xin,       // [nr][128] bf16, row n = zeros
    const int* __restrict__ info,      // [n]{padded_beg, deg}
    const int* __restrict__ adj,       // padded, 4-aligned rows; pads -> row n
    const u16* __restrict__ Wtl,       // [128][128] bf16 transposed
    const u16* __restrict__ Wtr,
    const float* __restrict__ bias,
    const float* __restrict__ Wfc,     // [128][2] f32
    const float* __restrict__ bfc,
    u16* __restrict__ hout,            // [nr][128] bf16 (layer 1); row n zeroed
    float* __restrict__ out,           // [n][2] f32 (layer 2)
    int n)
{
    constexpr int MT = 128;
    constexpr int LDK = 136;
    __shared__ u16 A_s[MT][LDK];       // 34.8 KB
    __shared__ u16 W_s[NF][LDK];       // 34.8 KB

    int t = threadIdx.x;
    int node0 = blockIdx.x * MT;

    // ---- stage Wl now; issue Wr + self loads early (latency hides under gather)
    u16x8 wrv[4], selfv[4];
    #pragma unroll
    for (int i = 0; i < 4; i++) {
        int idx = t + i * 512;             // 2048 chunks of 16 B
        int row = idx >> 4, ch = idx & 15;
        *(u16x8*)&W_s[row][ch * 8] = ((const u16x8*)Wtl)[row * 16 + ch];
        wrv[i] = ((const u16x8*)Wtr)[row * 16 + ch];
        int node = node0 + row;
        selfv[i] = (u16x8)0;
        if (node < n) selfv[i] = nt_load8(xin + (size_t)node * NF + ch * 8);
    }

    // ---- gather-mean phase: agg tile straight into A_s (static 4 nodes/group)
    {
        int grp = t >> 4, lane = t & 15;
        const char* xbase = (const char*)xin;
        u32 lo16 = (u32)lane * 16;

        for (int j = 0; j < 4; j++) {
            int m = grp * 4 + j;
            int node = node0 + m;
            float L[4] = {0.f, 0.f, 0.f, 0.f}, H[4] = {0.f, 0.f, 0.f, 0.f};
            int dg = 0;
            if (node < n) {
                int2 inf = *(const int2*)(info + 2 * node);
                dg = inf.y;
                const i32x4* ap = (const i32x4*)(adj + inf.x);
                int ng = (dg + 3) >> 2;

#define ROWU(nb) (*(const u32x4*)(xbase + (((u32)(nb) << 8) + lo16)))
#define ACC4(cur) { \
    u32x4 r0 = ROWU(cur[0]), r1 = ROWU(cur[1]), r2 = ROWU(cur[2]), r3 = ROWU(cur[3]); \
    _Pragma("unroll") \
    for (int k = 0; k < 4; k++) { \
        L[k] += (lo2f(r0[k]) + lo2f(r1[k])) + (lo2f(r2[k]) + lo2f(r3[k])); \
        H[k] += (hi2f(r0[k]) + hi2f(r1[k])) + (hi2f(r2[k]) + hi2f(r3[k])); \
    } }
                i32x4 ia, ib;
                if (ng >= 2) {
                    ia = __builtin_nontemporal_load(ap);
                    ib = __builtin_nontemporal_load(ap + 1);
                }
                int g = 0;
                while (g + 2 <= ng) {
                    i32x4 ca = ia, cb = ib;
                    g += 2;
                    if (g + 2 <= ng) {   // prefetch next pair under feature loads
                        ia = __builtin_nontemporal_load(ap + g);
                        ib = __builtin_nontemporal_load(ap + g + 1);
                    }
                    ACC4(ca);
                    ACC4(cb);
                }
                if (g < ng) {
                    i32x4 ca = __builtin_nontemporal_load(ap + g);
                    ACC4(ca);
                }
#undef ACC4
#undef ROWU
            }
            float invd = 1.0f / fmaxf((float)dg, 1.0f);
            u16x8 o;
            #pragma unroll
            for (int k = 0; k < 4; k++) {
                o[2 * k]     = f2b(L[k] * invd);
                o[2 * k + 1] = f2b(H[k] * invd);
            }
            *(u16x8*)&A_s[m][lane * 8] = o;    // node >= n -> zeros
        }
    }
    __syncthreads();

    // ---- MFMA pass 1: acc = agg @ Wl  (8 waves x 16 rows = 128)
    int l = t & 63;
    int lr = l & 15;
    int lko = (l >> 4) * 8;
    int m0 = (t >> 6) * 16;

    f32x4 acc[8];
    #pragma unroll
    for (int f = 0; f < 8; f++) acc[f] = (f32x4)0.f;

    #pragma unroll
    for (int ks = 0; ks < NF; ks += 32) {
        s16x8 a = *(const s16x8*)&A_s[m0 + lr][ks + lko];
        #pragma unroll
        for (int f = 0; f < 8; f++) {
            s16x8 b = *(const s16x8*)&W_s[f * 16 + lr][ks + lko];
            acc[f] = __builtin_amdgcn_mfma_f32_16x16x32_bf16(a, b, acc[f], 0, 0, 0);
        }
    }
    __syncthreads();

    // ---- write pre-staged Wr + self tile to LDS (loads completed during gather)
    #pragma unroll
    for (int i = 0; i < 4; i++) {
        int idx = t + i * 512;
        int row = idx >> 4, ch = idx & 15;
        *(u16x8*)&W_s[row][ch * 8] = wrv[i];
        *(u16x8*)&A_s[row][ch * 8] = selfv[i];
    }
    __syncthreads();

    // ---- MFMA pass 2: acc += self @ Wr
    #pragma unroll
    for (int ks = 0; ks < NF; ks += 32) {
        s16x8 a = *(const s16x8*)&A_s[m0 + lr][ks + lko];
        #pragma unroll
        for (int f = 0; f < 8; f++) {
            s16x8 b = *(const s16x8*)&W_s[f * 16 + lr][ks + lko];
            acc[f] = __builtin_amdgcn_mfma_f32_16x16x32_bf16(a, b, acc[f], 0, 0, 0);
        }
    }

    // ---- bias + relu -> bf16 tile in A_s
    __syncthreads();
    int rowb = m0 + (l >> 4) * 4;      // C layout: row=(lane>>4)*4+reg, col=lane&15
    #pragma unroll
    for (int f = 0; f < 8; f++) {
        float bc = bias[f * 16 + lr];
        #pragma unroll
        for (int r = 0; r < 4; r++) {
            float v = fmaxf(acc[f][r] + bc, 0.f);
            A_s[rowb + r][f * 16 + lr] = f2b(v);
        }
    }
    __syncthreads();

    if (!FC) {
        // write h row-major; node n (zero row) written explicitly
        #pragma unroll
        for (int i = 0; i < 4; i++) {
            int idx = t + i * 512;
            int row = idx >> 4, ch = idx & 15;
            int node = node0 + row;
            if (node < n)
                nt_store8(hout + (size_t)node * NF + ch * 8, *(u16x8*)&A_s[row][ch * 8]);
            else if (node == n)
                nt_store8(hout + (size_t)node * NF + ch * 8, (u16x8)0);
        }
    } else {
        int g = t >> 5, lane = t & 31;     // 16 groups of 32 lanes
        float2 wfc[4];
        #pragma unroll
        for (int j = 0; j < 4; j++) wfc[j] = ((const float2*)Wfc)[lane * 4 + j];
        float bf0 = bfc[0], bf1 = bfc[1];
        for (int m8 = 0; m8 < 8; m8++) {
            int m = g * 8 + m8;
            float p0 = 0.f, p1 = 0.f;
            #pragma unroll
            for (int j = 0; j < 4; j++) {
                float h = b2f(A_s[m][lane * 4 + j]);
                p0 += h * wfc[j].x;
                p1 += h * wfc[j].y;
            }
            #pragma unroll
            for (int s = 16; s; s >>= 1) {
                p0 += __shfl_down(p0, s, 32);
                p1 += __shfl_down(p1, s, 32);
            }
            int node = node0 + m;
            if (lane == 0 && node < n)
                *(float2*)(out + (size_t)node * 2) = make_float2(p0 + bf0, p1 + bf1);
        }
    }
}

extern "C" void kernel_launch(void* const* d_in, const int* in_sizes, int n_in,
                              void* d_out, int out_size, void* d_ws, size_t ws_size,
                              hipStream_t stream) {
    const float* x   = (const float*)d_in[0];
    const int*   ei  = (const int*)d_in[1];
    const float* W1l = (const float*)d_in[2];
    const float* b1  = (const float*)d_in[3];
    const float* W1r = (const float*)d_in[4];
    const float* W2l = (const float*)d_in[5];
    const float* b2  = (const float*)d_in[6];
    const float* W2r = (const float*)d_in[7];
    const float* Wfc = (const float*)d_in[8];
    const float* bfc = (const float*)d_in[9];

    const int n = in_sizes[0] / NF;   // 100000
    const int E = in_sizes[1] / 2;    // 1600000
    const int nr = n + 1;             // +1 zero row for pad slots
    const int NB = (n + BNODES - 1) >> SH;   // 196
    const int* src = ei;
    const int* dst = ei + E;

    // ws: xb | h1 | 4x Wt | adj(E+3n) | deg(n) | info(2n) |
    //     bsumB(256) | bcnt(256) | gcur(256) | boff(257) | pairs(E)
    u16* xb     = (u16*)d_ws;
    u16* h1     = xb + (size_t)nr * NF;
    u16* Wt1l   = h1 + (size_t)nr * NF;
    u16* Wt1r   = Wt1l + NF * NF;
    u16* Wt2l   = Wt1r + NF * NF;
    u16* Wt2r   = Wt2l + NF * NF;
    int* adj    = (int*)(Wt2r + NF * NF);
    int* deg    = adj + ((size_t)E + 3 * (size_t)n);
    int* info   = deg + n;
    int* bsumB  = info + 2 * (size_t)n;
    int* bcnt   = bsumB + 256;
    int* gcur   = bcnt + 256;
    int* boff   = gcur + 256;
    u32* pairs  = (u32*)(boff + 257);

    (void)hipMemsetAsync(bcnt, 0, 256 * sizeof(int), stream);

    // ---- bucketed CSR build (merged kernels)
    bhist_kernel<<<1024, 256, 0, stream>>>(dst, bcnt, E, NB);
    bscan_kernel<<<1, 256, 0, stream>>>(bcnt, boff, gcur, NB, E);
    scatter_kernel<<<(E + 4095) / 4096, 256, 0, stream>>>(src, dst, gcur, pairs, E, NB);
    degb_kernel<<<NB, 256, 0, stream>>>(pairs, boff, deg, bsumB, n);
    scan_excl_kernel<<<1, 256, 0, stream>>>(bsumB, NB);
    fillC_kernel<<<NB, 256, 0, stream>>>(pairs, boff, deg, bsumB, info, adj, n);

    cast_x_kernel<<<(nr * (NF / 8) + 255) / 256, 256, 0, stream>>>(x, xb, n, nr);
    cast_wt_kernel<<<dim3(64, 4), 256, 0, stream>>>(W1l, W1r, W2l, W2r,
                                                    Wt1l, Wt1r, Wt2l, Wt2r);

    int fb = (nr + 127) / 128;            // covers node n as well
    // layer 1: xb -> h1 (fused gather + GEMM)
    sage_fused_kernel<false><<<fb, 512, 0, stream>>>(
        xb, info, adj, Wt1l, Wt1r, b1, nullptr, nullptr, h1, nullptr, n);
    // layer 2 + FC: h1 -> out
    sage_fused_kernel<true><<<fb, 512, 0, stream>>>(
        h1, info, adj, Wt2l, Wt2r, b2, Wfc, bfc, nullptr, (float*)d_out, n);
}

// Round 16
// 263.672 us; speedup vs baseline: 1.2724x; 1.0791x over previous
//
#include <hip/hip_runtime.h>

#define NF 128          // features
#define SH 9            // bucket shift
#define BNODES 512      // nodes per bucket (1<<SH)
#define MAXNB 256       // max buckets (n <= 131072)

typedef unsigned short u16;
typedef unsigned int u32;
using u16x4 = __attribute__((ext_vector_type(4))) u16;
using u16x8 = __attribute__((ext_vector_type(8))) u16;
using s16x8 = __attribute__((ext_vector_type(8))) short;
using f32x4 = __attribute__((ext_vector_type(4))) float;
using u32x4 = __attribute__((ext_vector_type(4))) u32;
using i32x4 = __attribute__((ext_vector_type(4))) int;

__device__ inline float b2f(u16 b) {
    union { u32 u; float f; } c; c.u = (u32)b << 16; return c.f;
}
__device__ inline float lo2f(u32 w) {
    union { u32 u; float f; } c; c.u = w << 16; return c.f;
}
__device__ inline float hi2f(u32 w) {
    union { u32 u; float f; } c; c.u = w & 0xFFFF0000u; return c.f;
}
__device__ inline u16 f2b(float f) {
    union { float f; u32 u; } c; c.f = f;
    u32 u = c.u;
    u += 0x7FFFu + ((u >> 16) & 1u);   // round-to-nearest-even
    return (u16)(u >> 16);
}
__device__ inline u16x8 nt_load8(const u16* p) {
    u32x4 v = __builtin_nontemporal_load((const u32x4*)p);
    return *(u16x8*)&v;
}
__device__ inline void nt_store8(u16* p, u16x8 v) {
    __builtin_nontemporal_store(*(u32x4*)&v, (u32x4*)p);
}
__device__ inline int padded4(int d) { return (d + 3) & ~3; }

// ---------------- bucket histogram (LDS staged) ----------------
__global__ __launch_bounds__(256) void bhist_kernel(const int* __restrict__ dst,
                                                    int* __restrict__ bcnt, int E, int NB) {
    __shared__ int h[MAXNB];
    int t = threadIdx.x;
    h[t] = 0;
    __syncthreads();
    for (int e = blockIdx.x * 256 + t; e < E; e += gridDim.x * 256)
        atomicAdd(&h[__builtin_nontemporal_load(dst + e) >> SH], 1);
    __syncthreads();
    if (t < NB && h[t]) atomicAdd(&bcnt[t], h[t]);
}

// ---------------- bucket scan: boff (exclusive), gcur init ----------------
__global__ __launch_bounds__(256) void bscan_kernel(const int* __restrict__ bcnt,
                                                    int* __restrict__ boff,
                                                    int* __restrict__ gcur, int NB, int E) {
    __shared__ int ss[256];
    int t = threadIdx.x;
    int v = (t < NB) ? bcnt[t] : 0;
    ss[t] = v; __syncthreads();
    for (int off = 1; off < 256; off <<= 1) {
        int u = (t >= off) ? ss[t - off] : 0;
        __syncthreads();
        ss[t] += u;
        __syncthreads();
    }
    int excl = ss[t] - v;
    if (t < NB) { boff[t] = excl; gcur[t] = excl; }
    if (t == 0) boff[NB] = E;
}

// ---------------- generic in-place exclusive scan (<=256 entries) ----------------
__global__ __launch_bounds__(256) void scan_excl_kernel(int* __restrict__ a, int nb) {
    __shared__ int ss[256];
    int t = threadIdx.x;
    int v = (t < nb) ? a[t] : 0;
    ss[t] = v; __syncthreads();
    for (int off = 1; off < 256; off <<= 1) {
        int u = (t >= off) ? ss[t - off] : 0;
        __syncthreads();
        ss[t] += u;
        __syncthreads();
    }
    if (t < nb) a[t] = ss[t] - v;
}

// ---------------- scatter edges into bucket-sorted pairs (LDS staged) ----------------
// 4096 edges / block; packed = (dst&511)<<17 | src  (src < 2^17)
__global__ __launch_bounds__(256) void scatter_kernel(
    const int* __restrict__ src, const int* __restrict__ dst,
    int* __restrict__ gcur, u32* __restrict__ pairs, int E, int NB)
{
    __shared__ int hist[MAXNB];
    __shared__ int cstart[256];
    __shared__ int gbase[MAXNB];
    __shared__ u32 stage[4096];
    __shared__ u16 bmap[4096];
    int t = threadIdx.x;
    int base = blockIdx.x * 4096;

    hist[t] = 0;
    __syncthreads();

    u32 packed[16]; int bb[16]; int loff[16];
    #pragma unroll
    for (int j = 0; j < 16; j++) {
        int e = base + j * 256 + t;
        bb[j] = -1;
        if (e < E) {
            int d = __builtin_nontemporal_load(dst + e);
            int s = __builtin_nontemporal_load(src + e);
            int b = d >> SH;
            bb[j] = b;
            packed[j] = ((u32)(d & (BNODES - 1)) << 17) | (u32)s;
            loff[j] = atomicAdd(&hist[b], 1);
        }
    }
    __syncthreads();

    int hv = hist[t];
    cstart[t] = hv; __syncthreads();
    for (int off = 1; off < 256; off <<= 1) {
        int u = (t >= off) ? cstart[t - off] : 0;
        __syncthreads();
        cstart[t] += u;
        __syncthreads();
    }
    int excl = cstart[t] - hv;
    if (t < NB && hv > 0) gbase[t] = atomicAdd(&gcur[t], hv);
    __syncthreads();
    cstart[t] = excl;
    __syncthreads();

    #pragma unroll
    for (int j = 0; j < 16; j++) if (bb[j] >= 0) {
        int pos = cstart[bb[j]] + loff[j];
        stage[pos] = packed[j];
        bmap[pos] = (u16)bb[j];
    }
    __syncthreads();

    int total = min(4096, E - base);
    for (int k = t; k < total; k += 256) {
        u32 p = stage[k];
        int b = bmap[k];
        pairs[gbase[b] + (k - cstart[b])] = p;
    }
}

// ---------------- per-bucket degree count + padded bucket sum ----------------
__global__ __launch_bounds__(256) void degb_kernel(const u32* __restrict__ pairs,
                                                   const int* __restrict__ boff,
                                                   int* __restrict__ deg,
                                                   int* __restrict__ bsumB, int n) {
    __shared__ int dl[BNODES];
    __shared__ int red[256];
    int b = blockIdx.x, t = threadIdx.x;
    for (int i = t; i < BNODES; i += 256) dl[i] = 0;
    __syncthreads();
    int s = boff[b], e = boff[b + 1];
    for (int k = s + t; k < e; k += 256)
        atomicAdd(&dl[__builtin_nontemporal_load(pairs + k) >> 17], 1);
    __syncthreads();
    int nb0 = b << SH;
    int ps = 0;
    for (int i = t; i < BNODES; i += 256) {
        int d = dl[i];
        if (nb0 + i < n) { deg[nb0 + i] = d; ps += padded4(d); }
    }
    red[t] = ps; __syncthreads();
    for (int off = 128; off; off >>= 1) {
        if (t < off) red[t] += red[t + off];
        __syncthreads();
    }
    if (!t) bsumB[b] = red[0];
}

// ---------------- per-bucket: local padded scan + info + pads + CSR fill ----------------
__global__ __launch_bounds__(256) void fillC_kernel(const u32* __restrict__ pairs,
                                                    const int* __restrict__ boff,
                                                    const int* __restrict__ deg,
                                                    const int* __restrict__ bbase,
                                                    int* __restrict__ info,
                                                    int* __restrict__ adj, int n) {
    __shared__ int begl[BNODES];
    __shared__ int curl[BNODES];
    __shared__ int ss[256];
    int b = blockIdx.x, t = threadIdx.x;
    int nb0 = b << SH;
    int i0 = 2 * t, i1 = 2 * t + 1;
    int d0 = 0, d1 = 0;
    if (nb0 + i0 < n) d0 = deg[nb0 + i0];
    if (nb0 + i1 < n) d1 = deg[nb0 + i1];
    int p0 = padded4(d0), p1 = padded4(d1);
    int s = p0 + p1;
    ss[t] = s; __syncthreads();
    for (int off = 1; off < 256; off <<= 1) {
        int u = (t >= off) ? ss[t - off] : 0;
        __syncthreads();
        ss[t] += u;
        __syncthreads();
    }
    int beg0 = bbase[b] + ss[t] - s;
    int beg1 = beg0 + p0;
    if (nb0 + i1 < n) {
        i32x4 w = {beg0, d0, beg1, d1};
        ((i32x4*)info)[(nb0 >> 1) + t] = w;
    } else if (nb0 + i0 < n) {
        info[2 * (nb0 + i0)] = beg0; info[2 * (nb0 + i0) + 1] = d0;
    }
    begl[i0] = beg0; curl[i0] = 0;
    begl[i1] = beg1; curl[i1] = 0;
    if (nb0 + i0 < n) for (int p = d0; p < p0; p++) adj[beg0 + p] = n;
    if (nb0 + i1 < n) for (int p = d1; p < p1; p++) adj[beg1 + p] = n;
    __syncthreads();
    int sE = boff[b], eE = boff[b + 1];
    for (int k = sE + t; k < eE; k += 256) {
        u32 p = __builtin_nontemporal_load(pairs + k);
        int ld = p >> 17, sr = p & 0x1FFFF;
        int pos = atomicAdd(&curl[ld], 1);
        adj[begl[ld] + pos] = sr;
    }
}

// ---------------- cast x fp32 -> bf16 row-major [nr][128]; row n = 0 ----------------
__global__ __launch_bounds__(256) void cast_x_kernel(const float* __restrict__ x,
                                                     u16* __restrict__ xb, int n, int nr) {
    int i = blockIdx.x * 256 + threadIdx.x;   // one per 8 features
    if (i >= nr * (NF / 8)) return;
    int node = i >> 4, ch = i & 15;
    u16x8 o = (u16x8)0;
    if (node < n) {
        const float* p = x + (size_t)node * NF + ch * 8;
        f32x4 v0 = __builtin_nontemporal_load((const f32x4*)p);
        f32x4 v1 = __builtin_nontemporal_load((const f32x4*)(p + 4));
        o[0] = f2b(v0[0]); o[1] = f2b(v0[1]); o[2] = f2b(v0[2]); o[3] = f2b(v0[3]);
        o[4] = f2b(v1[0]); o[5] = f2b(v1[1]); o[6] = f2b(v1[2]); o[7] = f2b(v1[3]);
    }
    *(u16x8*)(xb + (size_t)node * NF + ch * 8) = o;
}

// ---------------- weights: fp32 [K][N] -> bf16 transposed [N][K] ----------------
__global__ void cast_wt_kernel(const float* __restrict__ w0, const float* __restrict__ w1,
                               const float* __restrict__ w2, const float* __restrict__ w3,
                               u16* __restrict__ o0, u16* __restrict__ o1,
                               u16* __restrict__ o2, u16* __restrict__ o3) {
    int m = blockIdx.y;
    const float* w = (m == 0) ? w0 : (m == 1) ? w1 : (m == 2) ? w2 : w3;
    u16* o = (m == 0) ? o0 : (m == 1) ? o1 : (m == 2) ? o2 : o3;
    int i = blockIdx.x * 256 + threadIdx.x;
    int k = i >> 7, nc = i & 127;
    o[nc * NF + k] = f2b(w[k * NF + nc]);
}

// ---------------- gather-mean, row-major; 16 lanes/node; 8-deep batched loads ----------------
// LDS-free, high occupancy. 256 threads = 16 nodes/block.
__global__ __launch_bounds__(256) void gather_kernel(
    const u16* __restrict__ xb,        // [nr][128], row n = zeros
    const int* __restrict__ info,      // [n]{padded_beg, deg}
    const int* __restrict__ adj,       // padded, 4-aligned rows; pads -> row n
    u16* __restrict__ agg,             // [nr][128]
    int n)
{
    int node = blockIdx.x * 16 + (threadIdx.x >> 4);
    if (node >= n) return;
    int lane = threadIdx.x & 15;
    const char* xbase = (const char*)xb;
    u32 lo16 = (u32)lane * 16;

    int2 inf = *(const int2*)(info + 2 * node);
    int beg = inf.x, deg = inf.y;
    const i32x4* ap = (const i32x4*)(adj + beg);   // 16B-aligned (beg % 4 == 0)
    int ng = (deg + 3) >> 2;

    float L[4] = {0.f, 0.f, 0.f, 0.f}, H[4] = {0.f, 0.f, 0.f, 0.f};

#define ROWU(nb) (*(const u32x4*)(xbase + (((u32)(nb) << 8) + lo16)))
#define ACC4(cur) { \
    u32x4 r0 = ROWU(cur[0]), r1 = ROWU(cur[1]), r2 = ROWU(cur[2]), r3 = ROWU(cur[3]); \
    _Pragma("unroll") \
    for (int k = 0; k < 4; k++) { \
        L[k] += (lo2f(r0[k]) + lo2f(r1[k])) + (lo2f(r2[k]) + lo2f(r3[k])); \
        H[k] += (hi2f(r0[k]) + hi2f(r1[k])) + (hi2f(r2[k]) + hi2f(r3[k])); \
    } }

    i32x4 ia, ib;
    if (ng >= 2) {
        ia = __builtin_nontemporal_load(ap);
        ib = __builtin_nontemporal_load(ap + 1);
    }
    int g = 0;
    while (g + 2 <= ng) {
        i32x4 ca = ia, cb = ib;
        g += 2;
        if (g + 2 <= ng) {   // prefetch next pair under feature loads
            ia = __builtin_nontemporal_load(ap + g);
            ib = __builtin_nontemporal_load(ap + g + 1);
        }
        ACC4(ca);
        ACC4(cb);
    }
    if (g < ng) {
        i32x4 ca = __builtin_nontemporal_load(ap + g);
        ACC4(ca);
    }
#undef ACC4
#undef ROWU

    float invd = 1.0f / fmaxf((float)deg, 1.0f);
    u16x8 o;
    #pragma unroll
    for (int k = 0; k < 4; k++) {
        o[2 * k]     = f2b(L[k] * invd);
        o[2 * k + 1] = f2b(H[k] * invd);
    }
    *(u16x8*)(agg + (size_t)node * NF + lane * 8) = o;
}

// ---------------- MFMA GEMM layer: relu(agg@Wl + self@Wr + b) (+FC epilogue) ----------------
// 64 nodes / block, 256 threads (4 waves x 16 output rows).
template <bool FC>
__global__ __launch_bounds__(256) void sage_mfma_kernel(
    const u16* __restrict__ agg,       // [nr][128] bf16
    const u16* __restrict__ selfb,     // [nr][128] bf16
    const u16* __restrict__ Wtl,       // [128][128] bf16 transposed
    const u16* __restrict__ Wtr,
    const float* __restrict__ bias,
    const float* __restrict__ Wfc,     // [128][2] f32
    const float* __restrict__ bfc,
    u16* __restrict__ hout,            // [nr][128] bf16 (layer 1); row n zeroed
    float* __restrict__ out,           // [n][2] f32 (layer 2)
    int n)
{
    constexpr int MT = 64;
    constexpr int LDK = 136;
    __shared__ u16 A_s[MT][LDK];
    __shared__ u16 W_s[NF][LDK];

    int t = threadIdx.x;
    int node0 = blockIdx.x * MT;

    #pragma unroll
    for (int i = 0; i < 8; i++) {
        int idx = t + i * 256;
        int row = idx >> 4, ch = idx & 15;
        *(u16x8*)&W_s[row][ch * 8] = ((const u16x8*)Wtl)[row * 16 + ch];
    }
    #pragma unroll
    for (int i = 0; i < 4; i++) {
        int idx = t + i * 256;
        int row = idx >> 4, ch = idx & 15;
        int node = node0 + row;
        u16x8 v = (u16x8)0;
        if (node < n) v = nt_load8(agg + (size_t)node * NF + ch * 8);
        *(u16x8*)&A_s[row][ch * 8] = v;
    }
    __syncthreads();

    int l = t & 63;
    int lr = l & 15;
    int lko = (l >> 4) * 8;
    int m0 = (t >> 6) * 16;

    f32x4 acc[8];
    #pragma unroll
    for (int f = 0; f < 8; f++) acc[f] = (f32x4)0.f;

    #pragma unroll
    for (int ks = 0; ks < NF; ks += 32) {
        s16x8 a = *(const s16x8*)&A_s[m0 + lr][ks + lko];
        #pragma unroll
        for (int f = 0; f < 8; f++) {
            s16x8 b = *(const s16x8*)&W_s[f * 16 + lr][ks + lko];
            acc[f] = __builtin_amdgcn_mfma_f32_16x16x32_bf16(a, b, acc[f], 0, 0, 0);
        }
    }
    __syncthreads();

    #pragma unroll
    for (int i = 0; i < 8; i++) {
        int idx = t + i * 256;
        int row = idx >> 4, ch = idx & 15;
        *(u16x8*)&W_s[row][ch * 8] = ((const u16x8*)Wtr)[row * 16 + ch];
    }
    #pragma unroll
    for (int i = 0; i < 4; i++) {
        int idx = t + i * 256;
        int row = idx >> 4, ch = idx & 15;
        int node = node0 + row;
        u16x8 v = (u16x8)0;
        if (node < n) v = nt_load8(selfb + (size_t)node * NF + ch * 8);
        *(u16x8*)&A_s[row][ch * 8] = v;
    }
    __syncthreads();

    #pragma unroll
    for (int ks = 0; ks < NF; ks += 32) {
        s16x8 a = *(const s16x8*)&A_s[m0 + lr][ks + lko];
        #pragma unroll
        for (int f = 0; f < 8; f++) {
            s16x8 b = *(const s16x8*)&W_s[f * 16 + lr][ks + lko];
            acc[f] = __builtin_amdgcn_mfma_f32_16x16x32_bf16(a, b, acc[f], 0, 0, 0);
        }
    }

    __syncthreads();
    int rowb = m0 + (l >> 4) * 4;      // C layout: row=(lane>>4)*4+reg, col=lane&15
    #pragma unroll
    for (int f = 0; f < 8; f++) {
        float bc = bias[f * 16 + lr];
        #pragma unroll
        for (int r = 0; r < 4; r++) {
            float v = fmaxf(acc[f][r] + bc, 0.f);
            A_s[rowb + r][f * 16 + lr] = f2b(v);
        }
    }
    __syncthreads();

    if (!FC) {
        #pragma unroll
        for (int i = 0; i < 4; i++) {
            int idx = t + i * 256;
            int row = idx >> 4, ch = idx & 15;
            int node = node0 + row;
            if (node < n)
                nt_store8(hout + (size_t)node * NF + ch * 8, *(u16x8*)&A_s[row][ch * 8]);
            else if (node == n)
                nt_store8(hout + (size_t)node * NF + ch * 8, (u16x8)0);
        }
    } else {
        int g = t >> 5, lane = t & 31;
        float2 wfc[4];
        #pragma unroll
        for (int j = 0; j < 4; j++) wfc[j] = ((const float2*)Wfc)[lane * 4 + j];
        float bf0 = bfc[0], bf1 = bfc[1];
        for (int m8 = 0; m8 < 8; m8++) {
            int m = g * 8 + m8;
            float p0 = 0.f, p1 = 0.f;
            #pragma unroll
            for (int j = 0; j < 4; j++) {
                float h = b2f(A_s[m][lane * 4 + j]);
                p0 += h * wfc[j].x;
                p1 += h * wfc[j].y;
            }
            #pragma unroll
            for (int s = 16; s; s >>= 1) {
                p0 += __shfl_down(p0, s, 32);
                p1 += __shfl_down(p1, s, 32);
            }
            int node = node0 + m;
            if (lane == 0 && node < n)
                *(float2*)(out + (size_t)node * 2) = make_float2(p0 + bf0, p1 + bf1);
        }
    }
}

extern "C" void kernel_launch(void* const* d_in, const int* in_sizes, int n_in,
                              void* d_out, int out_size, void* d_ws, size_t ws_size,
                              hipStream_t stream) {
    const float* x   = (const float*)d_in[0];
    const int*   ei  = (const int*)d_in[1];
    const float* W1l = (const float*)d_in[2];
    const float* b1  = (const float*)d_in[3];
    const float* W1r = (const float*)d_in[4];
    const float* W2l = (const float*)d_in[5];
    const float* b2  = (const float*)d_in[6];
    const float* W2r = (const float*)d_in[7];
    const float* Wfc = (const float*)d_in[8];
    const float* bfc = (const float*)d_in[9];

    const int n = in_sizes[0] / NF;   // 100000
    const int E = in_sizes[1] / 2;    // 1600000
    const int nr = n + 1;             // +1 zero row for pad slots
    const int NB = (n + BNODES - 1) >> SH;   // 196
    const int* src = ei;
    const int* dst = ei + E;

    // ws: xb | agg | h1 | 4x Wt | adj(E+3n) | deg(n) | info(2n) |
    //     bsumB(256) | bcnt(256) | gcur(256) | boff(257) | pairs(E)
    u16* xb     = (u16*)d_ws;
    u16* agg    = xb  + (size_t)nr * NF;
    u16* h1     = agg + (size_t)nr * NF;
    u16* Wt1l   = h1  + (size_t)nr * NF;
    u16* Wt1r   = Wt1l + NF * NF;
    u16* Wt2l   = Wt1r + NF * NF;
    u16* Wt2r   = Wt2l + NF * NF;
    int* adj    = (int*)(Wt2r + NF * NF);
    int* deg    = adj + ((size_t)E + 3 * (size_t)n);
    int* info   = deg + n;
    int* bsumB  = info + 2 * (size_t)n;
    int* bcnt   = bsumB + 256;
    int* gcur   = bcnt + 256;
    int* boff   = gcur + 256;
    u32* pairs  = (u32*)(boff + 257);

    (void)hipMemsetAsync(bcnt, 0, 256 * sizeof(int), stream);

    // ---- bucketed CSR build (merged kernels)
    bhist_kernel<<<1024, 256, 0, stream>>>(dst, bcnt, E, NB);
    bscan_kernel<<<1, 256, 0, stream>>>(bcnt, boff, gcur, NB, E);
    scatter_kernel<<<(E + 4095) / 4096, 256, 0, stream>>>(src, dst, gcur, pairs, E, NB);
    degb_kernel<<<NB, 256, 0, stream>>>(pairs, boff, deg, bsumB, n);
    scan_excl_kernel<<<1, 256, 0, stream>>>(bsumB, NB);
    fillC_kernel<<<NB, 256, 0, stream>>>(pairs, boff, deg, bsumB, info, adj, n);

    cast_x_kernel<<<(nr * (NF / 8) + 255) / 256, 256, 0, stream>>>(x, xb, n, nr);
    cast_wt_kernel<<<dim3(64, 4), 256, 0, stream>>>(W1l, W1r, W2l, W2r,
                                                    Wt1l, Wt1r, Wt2l, Wt2r);

    int gb = (n + 15) / 16;               // 6250
    int cb = (nr + 63) / 64;              // covers zero row n
    // layer 1
    gather_kernel<<<gb, 256, 0, stream>>>(xb, info, adj, agg, n);
    sage_mfma_kernel<false><<<cb, 256, 0, stream>>>(
        agg, xb, Wt1l, Wt1r, b1, nullptr, nullptr, h1, nullptr, n);
    // layer 2 + FC
    gather_kernel<<<gb, 256, 0, stream>>>(h1, info, adj, agg, n);
    sage_mfma_kernel<true><<<cb, 256, 0, stream>>>(
        agg, h1, Wt2l, Wt2r, b2, Wfc, bfc, nullptr, (float*)d_out, n);
}

// Round 17
// 258.081 us; speedup vs baseline: 1.3000x; 1.0217x over previous
//
#include <hip/hip_runtime.h>

#define NF 128          // features
#define SH 9            // bucket shift
#define BNODES 512      // nodes per bucket (1<<SH)
#define MAXNB 256       // max buckets (n <= 131072)

typedef unsigned short u16;
typedef unsigned int u32;
using u16x4 = __attribute__((ext_vector_type(4))) u16;
using u16x8 = __attribute__((ext_vector_type(8))) u16;
using s16x8 = __attribute__((ext_vector_type(8))) short;
using f32x4 = __attribute__((ext_vector_type(4))) float;
using u32x4 = __attribute__((ext_vector_type(4))) u32;
using i32x4 = __attribute__((ext_vector_type(4))) int;

__device__ inline float b2f(u16 b) {
    union { u32 u; float f; } c; c.u = (u32)b << 16; return c.f;
}
__device__ inline float lo2f(u32 w) {
    union { u32 u; float f; } c; c.u = w << 16; return c.f;
}
__device__ inline float hi2f(u32 w) {
    union { u32 u; float f; } c; c.u = w & 0xFFFF0000u; return c.f;
}
__device__ inline u16 f2b(float f) {
    union { float f; u32 u; } c; c.f = f;
    u32 u = c.u;
    u += 0x7FFFu + ((u >> 16) & 1u);   // round-to-nearest-even
    return (u16)(u >> 16);
}
__device__ inline u16x8 nt_load8(const u16* p) {
    u32x4 v = __builtin_nontemporal_load((const u32x4*)p);
    return *(u16x8*)&v;
}
__device__ inline void nt_store8(u16* p, u16x8 v) {
    __builtin_nontemporal_store(*(u32x4*)&v, (u32x4*)p);
}
__device__ inline int padded4(int d) { return (d + 3) & ~3; }

// ---------------- bucket histogram (LDS staged) ----------------
__global__ __launch_bounds__(256) void bhist_kernel(const int* __restrict__ dst,
                                                    int* __restrict__ bcnt, int E, int NB) {
    __shared__ int h[MAXNB];
    int t = threadIdx.x;
    h[t] = 0;
    __syncthreads();
    for (int e = blockIdx.x * 256 + t; e < E; e += gridDim.x * 256)
        atomicAdd(&h[__builtin_nontemporal_load(dst + e) >> SH], 1);
    __syncthreads();
    if (t < NB && h[t]) atomicAdd(&bcnt[t], h[t]);
}

// ---------------- bucket scan: boff (exclusive), gcur init ----------------
__global__ __launch_bounds__(256) void bscan_kernel(const int* __restrict__ bcnt,
                                                    int* __restrict__ boff,
                                                    int* __restrict__ gcur, int NB, int E) {
    __shared__ int ss[256];
    int t = threadIdx.x;
    int v = (t < NB) ? bcnt[t] : 0;
    ss[t] = v; __syncthreads();
    for (int off = 1; off < 256; off <<= 1) {
        int u = (t >= off) ? ss[t - off] : 0;
        __syncthreads();
        ss[t] += u;
        __syncthreads();
    }
    int excl = ss[t] - v;
    if (t < NB) { boff[t] = excl; gcur[t] = excl; }
    if (t == 0) boff[NB] = E;
}

// ---------------- generic in-place exclusive scan (<=256 entries) ----------------
__global__ __launch_bounds__(256) void scan_excl_kernel(int* __restrict__ a, int nb) {
    __shared__ int ss[256];
    int t = threadIdx.x;
    int v = (t < nb) ? a[t] : 0;
    ss[t] = v; __syncthreads();
    for (int off = 1; off < 256; off <<= 1) {
        int u = (t >= off) ? ss[t - off] : 0;
        __syncthreads();
        ss[t] += u;
        __syncthreads();
    }
    if (t < nb) a[t] = ss[t] - v;
}

// ---------------- scatter edges into bucket-sorted pairs (LDS staged) ----------------
// 4096 edges / block; packed = (dst&511)<<17 | src  (src < 2^17)
__global__ __launch_bounds__(256) void scatter_kernel(
    const int* __restrict__ src, const int* __restrict__ dst,
    int* __restrict__ gcur, u32* __restrict__ pairs, int E, int NB)
{
    __shared__ int hist[MAXNB];
    __shared__ int cstart[256];
    __shared__ int gbase[MAXNB];
    __shared__ u32 stage[4096];
    __shared__ u16 bmap[4096];
    int t = threadIdx.x;
    int base = blockIdx.x * 4096;

    hist[t] = 0;
    __syncthreads();

    u32 packed[16]; int bb[16]; int loff[16];
    #pragma unroll
    for (int j = 0; j < 16; j++) {
        int e = base + j * 256 + t;
        bb[j] = -1;
        if (e < E) {
            int d = __builtin_nontemporal_load(dst + e);
            int s = __builtin_nontemporal_load(src + e);
            int b = d >> SH;
            bb[j] = b;
            packed[j] = ((u32)(d & (BNODES - 1)) << 17) | (u32)s;
            loff[j] = atomicAdd(&hist[b], 1);
        }
    }
    __syncthreads();

    int hv = hist[t];
    cstart[t] = hv; __syncthreads();
    for (int off = 1; off < 256; off <<= 1) {
        int u = (t >= off) ? cstart[t - off] : 0;
        __syncthreads();
        cstart[t] += u;
        __syncthreads();
    }
    int excl = cstart[t] - hv;
    if (t < NB && hv > 0) gbase[t] = atomicAdd(&gcur[t], hv);
    __syncthreads();
    cstart[t] = excl;
    __syncthreads();

    #pragma unroll
    for (int j = 0; j < 16; j++) if (bb[j] >= 0) {
        int pos = cstart[bb[j]] + loff[j];
        stage[pos] = packed[j];
        bmap[pos] = (u16)bb[j];
    }
    __syncthreads();

    int total = min(4096, E - base);
    for (int k = t; k < total; k += 256) {
        u32 p = stage[k];
        int b = bmap[k];
        pairs[gbase[b] + (k - cstart[b])] = p;
    }
}

// ---------------- per-bucket degree count + padded bucket sum ----------------
__global__ __launch_bounds__(256) void degb_kernel(const u32* __restrict__ pairs,
                                                   const int* __restrict__ boff,
                                                   int* __restrict__ deg,
                                                   int* __restrict__ bsumB, int n) {
    __shared__ int dl[BNODES];
    __shared__ int red[256];
    int b = blockIdx.x, t = threadIdx.x;
    for (int i = t; i < BNODES; i += 256) dl[i] = 0;
    __syncthreads();
    int s = boff[b], e = boff[b + 1];
    for (int k = s + t; k < e; k += 256)
        atomicAdd(&dl[__builtin_nontemporal_load(pairs + k) >> 17], 1);
    __syncthreads();
    int nb0 = b << SH;
    int ps = 0;
    for (int i = t; i < BNODES; i += 256) {
        int d = dl[i];
        if (nb0 + i < n) { deg[nb0 + i] = d; ps += padded4(d); }
    }
    red[t] = ps; __syncthreads();
    for (int off = 128; off; off >>= 1) {
        if (t < off) red[t] += red[t + off];
        __syncthreads();
    }
    if (!t) bsumB[b] = red[0];
}

// ---------------- per-bucket: local padded scan + info + pads + CSR fill ----------------
__global__ __launch_bounds__(256) void fillC_kernel(const u32* __restrict__ pairs,
                                                    const int* __restrict__ boff,
                                                    const int* __restrict__ deg,
                                                    const int* __restrict__ bbase,
                                                    int* __restrict__ info,
                                                    int* __restrict__ adj, int n) {
    __shared__ int begl[BNODES];
    __shared__ int curl[BNODES];
    __shared__ int ss[256];
    int b = blockIdx.x, t = threadIdx.x;
    int nb0 = b << SH;
    int i0 = 2 * t, i1 = 2 * t + 1;
    int d0 = 0, d1 = 0;
    if (nb0 + i0 < n) d0 = deg[nb0 + i0];
    if (nb0 + i1 < n) d1 = deg[nb0 + i1];
    int p0 = padded4(d0), p1 = padded4(d1);
    int s = p0 + p1;
    ss[t] = s; __syncthreads();
    for (int off = 1; off < 256; off <<= 1) {
        int u = (t >= off) ? ss[t - off] : 0;
        __syncthreads();
        ss[t] += u;
        __syncthreads();
    }
    int beg0 = bbase[b] + ss[t] - s;
    int beg1 = beg0 + p0;
    if (nb0 + i1 < n) {
        i32x4 w = {beg0, d0, beg1, d1};
        ((i32x4*)info)[(nb0 >> 1) + t] = w;
    } else if (nb0 + i0 < n) {
        info[2 * (nb0 + i0)] = beg0; info[2 * (nb0 + i0) + 1] = d0;
    }
    begl[i0] = beg0; curl[i0] = 0;
    begl[i1] = beg1; curl[i1] = 0;
    if (nb0 + i0 < n) for (int p = d0; p < p0; p++) adj[beg0 + p] = n;
    if (nb0 + i1 < n) for (int p = d1; p < p1; p++) adj[beg1 + p] = n;
    __syncthreads();
    int sE = boff[b], eE = boff[b + 1];
    for (int k = sE + t; k < eE; k += 256) {
        u32 p = __builtin_nontemporal_load(pairs + k);
        int ld = p >> 17, sr = p & 0x1FFFF;
        int pos = atomicAdd(&curl[ld], 1);
        adj[begl[ld] + pos] = sr;
    }
}

// ---------------- cast x fp32 -> bf16 row-major [nr][128]; row n = 0 ----------------
__global__ __launch_bounds__(256) void cast_x_kernel(const float* __restrict__ x,
                                                     u16* __restrict__ xb, int n, int nr) {
    int i = blockIdx.x * 256 + threadIdx.x;   // one per 8 features
    if (i >= nr * (NF / 8)) return;
    int node = i >> 4, ch = i & 15;
    u16x8 o = (u16x8)0;
    if (node < n) {
        const float* p = x + (size_t)node * NF + ch * 8;
        f32x4 v0 = __builtin_nontemporal_load((const f32x4*)p);
        f32x4 v1 = __builtin_nontemporal_load((const f32x4*)(p + 4));
        o[0] = f2b(v0[0]); o[1] = f2b(v0[1]); o[2] = f2b(v0[2]); o[3] = f2b(v0[3]);
        o[4] = f2b(v1[0]); o[5] = f2b(v1[1]); o[6] = f2b(v1[2]); o[7] = f2b(v1[3]);
    }
    *(u16x8*)(xb + (size_t)node * NF + ch * 8) = o;
}

// ---------------- weights: fp32 [K][N] -> bf16 transposed [N][K] ----------------
__global__ void cast_wt_kernel(const float* __restrict__ w0, const float* __restrict__ w1,
                               const float* __restrict__ w2, const float* __restrict__ w3,
                               u16* __restrict__ o0, u16* __restrict__ o1,
                               u16* __restrict__ o2, u16* __restrict__ o3) {
    int m = blockIdx.y;
    const float* w = (m == 0) ? w0 : (m == 1) ? w1 : (m == 2) ? w2 : w3;
    u16* o = (m == 0) ? o0 : (m == 1) ? o1 : (m == 2) ? o2 : o3;
    int i = blockIdx.x * 256 + threadIdx.x;
    int k = i >> 7, nc = i & 127;
    o[nc * NF + k] = f2b(w[k * NF + nc]);
}

// ---------------- fused layer: gather-mean into LDS + dual MFMA + epilogue ----------------
// 512 threads, 128 nodes/block: 32 groups x 16 lanes, 4 serial nodes per group.
template <bool FC>
__global__ __launch_bounds__(512) void sage_fused_kernel(
    const u16* __restrict__ xin,       // [nr][128] bf16, row n = zeros
    const int* __restrict__ info,      // [n]{padded_beg, deg}
    const int* __restrict__ adj,       // padded, 4-aligned rows; pads -> row n
    const u16* __restrict__ Wtl,       // [128][128] bf16 transposed
    const u16* __restrict__ Wtr,
    const float* __restrict__ bias,
    const float* __restrict__ Wfc,     // [128][2] f32
    const float* __restrict__ bfc,
    u16* __restrict__ hout,            // [nr][128] bf16 (layer 1); row n zeroed
    float* __restrict__ out,           // [n][2] f32 (layer 2)
    int n)
{
    constexpr int MT = 128;
    constexpr int LDK = 136;
    __shared__ u16 A_s[MT][LDK];       // 34.8 KB
    __shared__ u16 W_s[NF][LDK];       // 34.8 KB

    int t = threadIdx.x;
    int node0 = blockIdx.x * MT;

    // ---- stage Wl early: latency hides under gather
    #pragma unroll
    for (int i = 0; i < 4; i++) {
        int idx = t + i * 512;             // 2048 chunks of 16 B
        int row = idx >> 4, ch = idx & 15;
        *(u16x8*)&W_s[row][ch * 8] = ((const u16x8*)Wtl)[row * 16 + ch];
    }

    // ---- gather-mean phase: agg tile straight into A_s
    {
        int grp = t >> 4, lane = t & 15;
        const char* xbase = (const char*)xin;
        u32 lo16 = (u32)lane * 16;

        for (int j = 0; j < 4; j++) {
            int m = grp * 4 + j;
            int node = node0 + m;
            float L[4] = {0.f, 0.f, 0.f, 0.f}, H[4] = {0.f, 0.f, 0.f, 0.f};
            int dg = 0;
            if (node < n) {
                int2 inf = *(const int2*)(info + 2 * node);
                dg = inf.y;
                const i32x4* ap = (const i32x4*)(adj + inf.x);
                int ng = (dg + 3) >> 2;

#define ROWU(nb) (*(const u32x4*)(xbase + (((u32)(nb) << 8) + lo16)))
#define ACC4(cur) { \
    u32x4 r0 = ROWU(cur[0]), r1 = ROWU(cur[1]), r2 = ROWU(cur[2]), r3 = ROWU(cur[3]); \
    _Pragma("unroll") \
    for (int k = 0; k < 4; k++) { \
        L[k] += (lo2f(r0[k]) + lo2f(r1[k])) + (lo2f(r2[k]) + lo2f(r3[k])); \
        H[k] += (hi2f(r0[k]) + hi2f(r1[k])) + (hi2f(r2[k]) + hi2f(r3[k])); \
    } }
                i32x4 ia, ib;
                if (ng >= 2) {
                    ia = __builtin_nontemporal_load(ap);
                    ib = __builtin_nontemporal_load(ap + 1);
                }
                int g = 0;
                while (g + 2 <= ng) {
                    i32x4 ca = ia, cb = ib;
                    g += 2;
                    if (g + 2 <= ng) {   // prefetch next pair under feature loads
                        ia = __builtin_nontemporal_load(ap + g);
                        ib = __builtin_nontemporal_load(ap + g + 1);
                    }
                    ACC4(ca);
                    ACC4(cb);
                }
                if (g < ng) {
                    i32x4 ca = __builtin_nontemporal_load(ap + g);
                    ACC4(ca);
                }
#undef ACC4
#undef ROWU
            }
            float invd = 1.0f / fmaxf((float)dg, 1.0f);
            u16x8 o;
            #pragma unroll
            for (int k = 0; k < 4; k++) {
                o[2 * k]     = f2b(L[k] * invd);
                o[2 * k + 1] = f2b(H[k] * invd);
            }
            *(u16x8*)&A_s[m][lane * 8] = o;    // node >= n -> zeros
        }
    }
    __syncthreads();

    // ---- MFMA pass 1: acc = agg @ Wl  (8 waves x 16 rows = 128)
    int l = t & 63;
    int lr = l & 15;
    int lko = (l >> 4) * 8;
    int m0 = (t >> 6) * 16;

    f32x4 acc[8];
    #pragma unroll
    for (int f = 0; f < 8; f++) acc[f] = (f32x4)0.f;

    #pragma unroll
    for (int ks = 0; ks < NF; ks += 32) {
        s16x8 a = *(const s16x8*)&A_s[m0 + lr][ks + lko];
        #pragma unroll
        for (int f = 0; f < 8; f++) {
            s16x8 b = *(const s16x8*)&W_s[f * 16 + lr][ks + lko];
            acc[f] = __builtin_amdgcn_mfma_f32_16x16x32_bf16(a, b, acc[f], 0, 0, 0);
        }
    }
    __syncthreads();

    // ---- stage Wr + self tile
    #pragma unroll
    for (int i = 0; i < 4; i++) {
        int idx = t + i * 512;
        int row = idx >> 4, ch = idx & 15;
        *(u16x8*)&W_s[row][ch * 8] = ((const u16x8*)Wtr)[row * 16 + ch];
    }
    #pragma unroll
    for (int i = 0; i < 4; i++) {
        int idx = t + i * 512;                 // 2048 chunks
        int row = idx >> 4, ch = idx & 15;
        int node = node0 + row;
        u16x8 v = (u16x8)0;
        if (node < n) v = nt_load8(xin + (size_t)node * NF + ch * 8);
        *(u16x8*)&A_s[row][ch * 8] = v;
    }
    __syncthreads();

    // ---- MFMA pass 2: acc += self @ Wr
    #pragma unroll
    for (int ks = 0; ks < NF; ks += 32) {
        s16x8 a = *(const s16x8*)&A_s[m0 + lr][ks + lko];
        #pragma unroll
        for (int f = 0; f < 8; f++) {
            s16x8 b = *(const s16x8*)&W_s[f * 16 + lr][ks + lko];
            acc[f] = __builtin_amdgcn_mfma_f32_16x16x32_bf16(a, b, acc[f], 0, 0, 0);
        }
    }

    // ---- bias + relu -> bf16 tile in A_s
    __syncthreads();
    int rowb = m0 + (l >> 4) * 4;      // C layout: row=(lane>>4)*4+reg, col=lane&15
    #pragma unroll
    for (int f = 0; f < 8; f++) {
        float bc = bias[f * 16 + lr];
        #pragma unroll
        for (int r = 0; r < 4; r++) {
            float v = fmaxf(acc[f][r] + bc, 0.f);
            A_s[rowb + r][f * 16 + lr] = f2b(v);
        }
    }
    __syncthreads();

    if (!FC) {
        // write h row-major; node n (zero row) written explicitly
        #pragma unroll
        for (int i = 0; i < 4; i++) {
            int idx = t + i * 512;
            int row = idx >> 4, ch = idx & 15;
            int node = node0 + row;
            if (node < n)
                nt_store8(hout + (size_t)node * NF + ch * 8, *(u16x8*)&A_s[row][ch * 8]);
            else if (node == n)
                nt_store8(hout + (size_t)node * NF + ch * 8, (u16x8)0);
        }
    } else {
        int g = t >> 5, lane = t & 31;     // 16 groups of 32 lanes
        float2 wfc[4];
        #pragma unroll
        for (int j = 0; j < 4; j++) wfc[j] = ((const float2*)Wfc)[lane * 4 + j];
        float bf0 = bfc[0], bf1 = bfc[1];
        for (int m8 = 0; m8 < 8; m8++) {
            int m = g * 8 + m8;
            float p0 = 0.f, p1 = 0.f;
            #pragma unroll
            for (int j = 0; j < 4; j++) {
                float h = b2f(A_s[m][lane * 4 + j]);
                p0 += h * wfc[j].x;
                p1 += h * wfc[j].y;
            }
            #pragma unroll
            for (int s = 16; s; s >>= 1) {
                p0 += __shfl_down(p0, s, 32);
                p1 += __shfl_down(p1, s, 32);
            }
            int node = node0 + m;
            if (lane == 0 && node < n)
                *(float2*)(out + (size_t)node * 2) = make_float2(p0 + bf0, p1 + bf1);
        }
    }
}

extern "C" void kernel_launch(void* const* d_in, const int* in_sizes, int n_in,
                              void* d_out, int out_size, void* d_ws, size_t ws_size,
                              hipStream_t stream) {
    const float* x   = (const float*)d_in[0];
    const int*   ei  = (const int*)d_in[1];
    const float* W1l = (const float*)d_in[2];
    const float* b1  = (const float*)d_in[3];
    const float* W1r = (const float*)d_in[4];
    const float* W2l = (const float*)d_in[5];
    const float* b2  = (const float*)d_in[6];
    const float* W2r = (const float*)d_in[7];
    const float* Wfc = (const float*)d_in[8];
    const float* bfc = (const float*)d_in[9];

    const int n = in_sizes[0] / NF;   // 100000
    const int E = in_sizes[1] / 2;    // 1600000
    const int nr = n + 1;             // +1 zero row for pad slots
    const int NB = (n + BNODES - 1) >> SH;   // 196
    const int* src = ei;
    const int* dst = ei + E;

    // ws: xb | h1 | 4x Wt | adj(E+3n) | deg(n) | info(2n) |
    //     bsumB(256) | bcnt(256) | gcur(256) | boff(257) | pairs(E)
    u16* xb     = (u16*)d_ws;
    u16* h1     = xb + (size_t)nr * NF;
    u16* Wt1l   = h1 + (size_t)nr * NF;
    u16* Wt1r   = Wt1l + NF * NF;
    u16* Wt2l   = Wt1r + NF * NF;
    u16* Wt2r   = Wt2l + NF * NF;
    int* adj    = (int*)(Wt2r + NF * NF);
    int* deg    = adj + ((size_t)E + 3 * (size_t)n);
    int* info   = deg + n;
    int* bsumB  = info + 2 * (size_t)n;
    int* bcnt   = bsumB + 256;
    int* gcur   = bcnt + 256;
    int* boff   = gcur + 256;
    u32* pairs  = (u32*)(boff + 257);

    (void)hipMemsetAsync(bcnt, 0, 256 * sizeof(int), stream);

    // ---- bucketed CSR build (merged kernels)
    bhist_kernel<<<1024, 256, 0, stream>>>(dst, bcnt, E, NB);
    bscan_kernel<<<1, 256, 0, stream>>>(bcnt, boff, gcur, NB, E);
    scatter_kernel<<<(E + 4095) / 4096, 256, 0, stream>>>(src, dst, gcur, pairs, E, NB);
    degb_kernel<<<NB, 256, 0, stream>>>(pairs, boff, deg, bsumB, n);
    scan_excl_kernel<<<1, 256, 0, stream>>>(bsumB, NB);
    fillC_kernel<<<NB, 256, 0, stream>>>(pairs, boff, deg, bsumB, info, adj, n);

    cast_x_kernel<<<(nr * (NF / 8) + 255) / 256, 256, 0, stream>>>(x, xb, n, nr);
    cast_wt_kernel<<<dim3(64, 4), 256, 0, stream>>>(W1l, W1r, W2l, W2r,
                                                    Wt1l, Wt1r, Wt2l, Wt2r);

    int fb = (nr + 127) / 128;            // covers node n as well
    // layer 1: xb -> h1 (fused gather + GEMM)
    sage_fused_kernel<false><<<fb, 512, 0, stream>>>(
        xb, info, adj, Wt1l, Wt1r, b1, nullptr, nullptr, h1, nullptr, n);
    // layer 2 + FC: h1 -> out
    sage_fused_kernel<true><<<fb, 512, 0, stream>>>(
        h1, info, adj, Wt2l, Wt2r, b2, Wfc, bfc, nullptr, (float*)d_out, n);
}